// Round 2
// baseline (326.144 us; speedup 1.0000x reference)
//
#include <hip/hip_runtime.h>
#include <stdint.h>

typedef __bf16 bf16x8 __attribute__((ext_vector_type(8)));
typedef __bf16 bf16x4v __attribute__((ext_vector_type(4)));
typedef float  f32x16 __attribute__((ext_vector_type(16)));
typedef float  f32x4t __attribute__((ext_vector_type(4)));
typedef unsigned int u32x2 __attribute__((ext_vector_type(2)));

// ---- ws layout (bytes) ----
#define WS_W1E 0            // 256*64 bf16  = 32 KB
#define WS_W2  32768        // 256*256 bf16 = 128 KB
#define WS_R   163840       // 4*256*256 f32 = 1 MiB   Rt[b][n][o] (incl. b1)
#define WS_CT  1212416      // 4*256*256 bf16 = 512 KB Ct[b][m][o]

// ---------------- pre-kernel 1: weights -> bf16 ----------------
__global__ void prep_weights(const float* __restrict__ W1, const float* __restrict__ W2,
                             __bf16* __restrict__ w1e, __bf16* __restrict__ w2b) {
    int i = blockIdx.x * 256 + threadIdx.x;
    if (i < 256 * 64) {
        int o = i >> 6, e = i & 63;
        w1e[i] = (__bf16)W1[o * 320 + e];
    }
    int j = i - 256 * 64;
    if (j >= 0 && j < 256 * 256) w2b[j] = (__bf16)W2[j];
}

// ---------------- pre-kernel 2: R/C rank-1 terms ----------------
// Rt[b][j][o] = b1[o] + sum_c W1[o][64+c]*node[b][c][j]   (fp32)
// Ct[b][j][o] =         sum_c W1[o][192+c]*node[b][c][j]  (bf16)
// grid 64 = b(4) x jc(16); 256 thr = o. node tile staged in LDS.
__global__ __launch_bounds__(256) void prep_rc(
    const float* __restrict__ W1, const float* __restrict__ b1,
    const float* __restrict__ node, float* __restrict__ Rt,
    __bf16* __restrict__ Ctb) {
    __shared__ float nds[128 * 16];
    const int b = blockIdx.x >> 4, j0 = (blockIdx.x & 15) * 16;
    const int o = threadIdx.x;
    {
        int c = threadIdx.x >> 1, jh = (threadIdx.x & 1) * 8;
        const float* src = node + b * 32768 + c * 256 + j0 + jh;
        *(float4*)&nds[c * 16 + jh] = *(const float4*)src;
        *(float4*)&nds[c * 16 + jh + 4] = *(const float4*)(src + 4);
    }
    __syncthreads();
    float aR[16], aC[16];
#pragma unroll
    for (int j = 0; j < 16; ++j) { aR[j] = 0.f; aC[j] = 0.f; }
    const float* wr = W1 + o * 320 + 64;
    const float* wc = W1 + o * 320 + 192;
    for (int c4 = 0; c4 < 32; ++c4) {
        float4 wrv = *(const float4*)(wr + c4 * 4);
        float4 wcv = *(const float4*)(wc + c4 * 4);
        const float* wrp = (const float*)&wrv;
        const float* wcp = (const float*)&wcv;
#pragma unroll
        for (int r = 0; r < 4; ++r) {
            const f32x4t* nrow = (const f32x4t*)&nds[(c4 * 4 + r) * 16];
            f32x4t n0 = nrow[0], n1 = nrow[1], n2 = nrow[2], n3 = nrow[3];
#pragma unroll
            for (int q = 0; q < 4; ++q) {
                aR[q]      = fmaf(wrp[r], n0[q], aR[q]);
                aR[q + 4]  = fmaf(wrp[r], n1[q], aR[q + 4]);
                aR[q + 8]  = fmaf(wrp[r], n2[q], aR[q + 8]);
                aR[q + 12] = fmaf(wrp[r], n3[q], aR[q + 12]);
                aC[q]      = fmaf(wcp[r], n0[q], aC[q]);
                aC[q + 4]  = fmaf(wcp[r], n1[q], aC[q + 4]);
                aC[q + 8]  = fmaf(wcp[r], n2[q], aC[q + 8]);
                aC[q + 12] = fmaf(wcp[r], n3[q], aC[q + 12]);
            }
        }
    }
    float bb = b1[o];
#pragma unroll
    for (int j = 0; j < 16; ++j) {
        int idx = ((b * 256 + j0 + j) << 8) + o;
        Rt[idx] = aR[j] + bb;
        Ctb[idx] = (__bf16)aC[j];
    }
}

// ---------------- main fused kernel ----------------
// 512 blocks x 256 thr (4 waves, 2 blocks/CU). Block = (b, m0) fixed, n = n0..n0+7.
// Wave owns 64 och. A2 (W2) persistent in regs (128); A1 reloaded from L2 per tile
// (transient); acc reused between layers (64); edge prefetched into 16 regs during
// the L2-MFMA phase of the previous tile. Peak ~247 regs -> no spill (watch WRITE_SIZE).
__device__ inline void zero_acc(f32x16 acc[2][2]) {
#pragma unroll
    for (int i = 0; i < 2; ++i)
#pragma unroll
        for (int j = 0; j < 2; ++j)
#pragma unroll
            for (int k = 0; k < 16; ++k) acc[i][j][k] = 0.f;
}

__global__ __launch_bounds__(256, 2) void fused_main(
    const float* __restrict__ edge, const __bf16* __restrict__ w1e,
    const __bf16* __restrict__ w2, const float* __restrict__ Rt,
    const __bf16* __restrict__ Ctb, const float* __restrict__ b2,
    const float* __restrict__ W3, const float* __restrict__ b3,
    float* __restrict__ out) {
    __shared__ unsigned int lds_e[64 * 36];   // edge tile [m][e-pair] bf16x2, stride 36 dw (odd s -> balanced banks)
    __shared__ unsigned int lds_h1[64 * 140]; // h1 tile [pix][ch/2] bf16x2, stride 140 dw
    __shared__ float lds_p[64 * 9];

    const int tid = threadIdx.x;
    const int wid = tid >> 6;
    const int lane = tid & 63;
    const int p31 = lane & 31;
    const int hi = lane >> 5;
    const int obase = wid * 64;

    const int blk = blockIdx.x;
    const int b   = blk >> 7;          // 4
    const int m0  = ((blk >> 5) & 3) << 6; // 4 x 64-pixel column tiles
    const int n0  = (blk & 31) << 3;   // 32 x 8-row groups

    // ---- persistent A2 fragments (W2): 128 VGPRs ----
    bf16x8 A2[2][16];
#pragma unroll
    for (int mb = 0; mb < 2; ++mb)
#pragma unroll
        for (int ks = 0; ks < 16; ++ks)
            A2[mb][ks] = *(const bf16x8*)(w2 + (obase + mb * 32 + p31) * 256 + ks * 16 + hi * 8);

    const float4* eg = (const float4*)edge;
    const int a_ = tid & 15;           // m-group (4 pixels)
    const int epb = tid >> 4;          // e-pair base 0..15
    float4 pf[4];

    // prefetch edge tile for row n into pf
#define PREFETCH(nn)                                                        \
    {                                                                       \
        _Pragma("unroll")                                                   \
        for (int r = 0; r < 2; ++r) {                                       \
            int ep = r * 16 + epb;                                          \
            int f4 = (b * 64 + ep * 2) * 16384 + (nn) * 64 + (m0 >> 2) + a_;\
            pf[r * 2]     = eg[f4];                                         \
            pf[r * 2 + 1] = eg[f4 + 16384];                                 \
        }                                                                   \
    }

    PREFETCH(n0);

    f32x16 acc[2][2];
    for (int it = 0; it < 8; ++it) {
        const int n = n0 + it;

        // ---- stage pf -> lds_e (transpose to [m][e], bf16) ----
#pragma unroll
        for (int r = 0; r < 2; ++r) {
            int ep = r * 16 + epb;
            const float* p0 = (const float*)&pf[r * 2];
            const float* p1 = (const float*)&pf[r * 2 + 1];
#pragma unroll
            for (int i = 0; i < 4; ++i) {
                union { __bf16 h[2]; unsigned int u; } t;
                t.h[0] = (__bf16)p0[i];
                t.h[1] = (__bf16)p1[i];
                lds_e[(a_ * 4 + i) * 36 + ep] = t.u;
            }
        }
        // ---- A1 (W1e) fragments for this tile: transient, from L2 ----
        bf16x8 A1[2][4];
#pragma unroll
        for (int mb = 0; mb < 2; ++mb)
#pragma unroll
            for (int ks = 0; ks < 4; ++ks)
                A1[mb][ks] = *(const bf16x8*)(w1e + (obase + mb * 32 + p31) * 64 + ks * 16 + hi * 8);
        __syncthreads();

        // ---- layer 1: W1e(64K) @ edge ----
        zero_acc(acc);
#pragma unroll
        for (int ks = 0; ks < 4; ++ks) {
            bf16x8 B1[2];
#pragma unroll
            for (int nb = 0; nb < 2; ++nb)
                B1[nb] = *(const bf16x8*)&lds_e[(nb * 32 + p31) * 36 + ks * 8 + hi * 4];
#pragma unroll
            for (int mb = 0; mb < 2; ++mb) {
                acc[mb][0] = __builtin_amdgcn_mfma_f32_32x32x16_bf16(A1[mb][ks], B1[0], acc[mb][0], 0, 0, 0);
                acc[mb][1] = __builtin_amdgcn_mfma_f32_32x32x16_bf16(A1[mb][ks], B1[1], acc[mb][1], 0, 0, 0);
            }
        }

        // ---- epilogue 1: + Rt[n] (f32) + Ct[m] (bf16), relu -> lds_h1 ----
        const int nRow = (b * 256 + n) << 8;
#pragma unroll
        for (int mb = 0; mb < 2; ++mb) {
#pragma unroll
            for (int rg = 0; rg < 4; ++rg) {
                int och = obase + mb * 32 + 8 * rg + 4 * hi;
                f32x4t Rv = *(const f32x4t*)(Rt + nRow + och);
#pragma unroll
                for (int nb = 0; nb < 2; ++nb) {
                    int pix = nb * 32 + p31;
                    bf16x4v Cv = *(const bf16x4v*)(Ctb + ((b * 256 + m0 + pix) << 8) + och);
                    union { __bf16 h[4]; u32x2 u; } t;
#pragma unroll
                    for (int rr = 0; rr < 4; ++rr) {
                        float v = acc[mb][nb][rg * 4 + rr] + Rv[rr] + (float)Cv[rr];
                        t.h[rr] = (__bf16)fmaxf(v, 0.f);
                    }
                    *(u32x2*)&lds_h1[pix * 140 + (och >> 1)] = t.u;
                }
            }
        }
        // ---- prefetch next tile's edge (A1 dead; overlaps L2 MFMA) ----
        if (it < 7) PREFETCH(n + 1);
        __syncthreads();

        // ---- layer 2: W2(256K) @ h1 ----
        zero_acc(acc);
#pragma unroll
        for (int ks = 0; ks < 16; ++ks) {
            bf16x8 B2[2];
#pragma unroll
            for (int nb = 0; nb < 2; ++nb)
                B2[nb] = *(const bf16x8*)&lds_h1[(nb * 32 + p31) * 140 + ks * 8 + hi * 4];
#pragma unroll
            for (int mb = 0; mb < 2; ++mb) {
                acc[mb][0] = __builtin_amdgcn_mfma_f32_32x32x16_bf16(A2[mb][ks], B2[0], acc[mb][0], 0, 0, 0);
                acc[mb][1] = __builtin_amdgcn_mfma_f32_32x32x16_bf16(A2[mb][ks], B2[1], acc[mb][1], 0, 0, 0);
            }
        }

        // ---- epilogue 2: +b2, relu, dot W3 (fp32) ----
        float part0 = 0.f, part1 = 0.f;
#pragma unroll
        for (int mb = 0; mb < 2; ++mb) {
#pragma unroll
            for (int rg = 0; rg < 4; ++rg) {
                int och = obase + mb * 32 + 8 * rg + 4 * hi;
                f32x4t b2v = *(const f32x4t*)(b2 + och);
                f32x4t w3v = *(const f32x4t*)(W3 + och);
#pragma unroll
                for (int rr = 0; rr < 4; ++rr) {
                    float h0 = fmaxf(acc[mb][0][rg * 4 + rr] + b2v[rr], 0.f);
                    float h1v = fmaxf(acc[mb][1][rg * 4 + rr] + b2v[rr], 0.f);
                    part0 = fmaf(w3v[rr], h0, part0);
                    part1 = fmaf(w3v[rr], h1v, part1);
                }
            }
        }
        lds_p[(0 * 32 + p31) * 9 + wid * 2 + hi] = part0;
        lds_p[(1 * 32 + p31) * 9 + wid * 2 + hi] = part1;
        __syncthreads();

        if (tid < 64) {
            float s = b3[0];
#pragma unroll
            for (int k = 0; k < 8; ++k) s += lds_p[tid * 9 + k];
            out[((b * 256 + n) << 8) + m0 + tid] = s;
        }
    }
#undef PREFETCH
}

extern "C" void kernel_launch(void* const* d_in, const int* in_sizes, int n_in,
                              void* d_out, int out_size, void* d_ws, size_t ws_size,
                              hipStream_t stream) {
    const float* edge = (const float*)d_in[0];
    const float* node = (const float*)d_in[1];
    const float* W1   = (const float*)d_in[2];
    const float* b1   = (const float*)d_in[3];
    const float* W2   = (const float*)d_in[4];
    const float* b2   = (const float*)d_in[5];
    const float* W3   = (const float*)d_in[6];
    const float* b3   = (const float*)d_in[7];
    char* ws = (char*)d_ws;
    __bf16* w1e = (__bf16*)(ws + WS_W1E);
    __bf16* w2b = (__bf16*)(ws + WS_W2);
    float*  Rt  = (float*)(ws + WS_R);
    __bf16* Ctb = (__bf16*)(ws + WS_CT);

    prep_weights<<<320, 256, 0, stream>>>(W1, W2, w1e, w2b);
    prep_rc<<<64, 256, 0, stream>>>(W1, b1, node, Rt, Ctb);
    fused_main<<<512, 256, 0, stream>>>(edge, w1e, w2b, Rt, Ctb, b2, W3, b3, (float*)d_out);
}

// Round 3
// 318.855 us; speedup vs baseline: 1.0229x; 1.0229x over previous
//
#include <hip/hip_runtime.h>
#include <stdint.h>

typedef __bf16 bf16x8 __attribute__((ext_vector_type(8)));
typedef __bf16 bf16x4v __attribute__((ext_vector_type(4)));
typedef float  f32x16 __attribute__((ext_vector_type(16)));
typedef float  f32x4t __attribute__((ext_vector_type(4)));
typedef unsigned int u32x2 __attribute__((ext_vector_type(2)));

// ---- ws layout (bytes) ----
#define WS_W1E 0            // 256*64 bf16  = 32 KB
#define WS_W2  32768        // 256*256 bf16 = 128 KB
#define WS_R   163840       // 4*256*256 f32 = 1 MiB   Rt[b][n][o] (incl. b1)
#define WS_CT  1212416      // 4*256*256 bf16 = 512 KB Ct[b][m][o]

// ---------------- pre-kernel 1: weights -> bf16 ----------------
__global__ void prep_weights(const float* __restrict__ W1, const float* __restrict__ W2,
                             __bf16* __restrict__ w1e, __bf16* __restrict__ w2b) {
    int i = blockIdx.x * 256 + threadIdx.x;
    if (i < 256 * 64) {
        int o = i >> 6, e = i & 63;
        w1e[i] = (__bf16)W1[o * 320 + e];
    }
    int j = i - 256 * 64;
    if (j >= 0 && j < 256 * 256) w2b[j] = (__bf16)W2[j];
}

// ---------------- pre-kernel 2: R/C rank-1 terms ----------------
__global__ __launch_bounds__(256) void prep_rc(
    const float* __restrict__ W1, const float* __restrict__ b1,
    const float* __restrict__ node, float* __restrict__ Rt,
    __bf16* __restrict__ Ctb) {
    __shared__ float nds[128 * 16];
    const int b = blockIdx.x >> 4, j0 = (blockIdx.x & 15) * 16;
    const int o = threadIdx.x;
    {
        int c = threadIdx.x >> 1, jh = (threadIdx.x & 1) * 8;
        const float* src = node + b * 32768 + c * 256 + j0 + jh;
        *(float4*)&nds[c * 16 + jh] = *(const float4*)src;
        *(float4*)&nds[c * 16 + jh + 4] = *(const float4*)(src + 4);
    }
    __syncthreads();
    float aR[16], aC[16];
#pragma unroll
    for (int j = 0; j < 16; ++j) { aR[j] = 0.f; aC[j] = 0.f; }
    const float* wr = W1 + o * 320 + 64;
    const float* wc = W1 + o * 320 + 192;
    for (int c4 = 0; c4 < 32; ++c4) {
        float4 wrv = *(const float4*)(wr + c4 * 4);
        float4 wcv = *(const float4*)(wc + c4 * 4);
        const float* wrp = (const float*)&wrv;
        const float* wcp = (const float*)&wcv;
#pragma unroll
        for (int r = 0; r < 4; ++r) {
            const f32x4t* nrow = (const f32x4t*)&nds[(c4 * 4 + r) * 16];
            f32x4t n0 = nrow[0], n1 = nrow[1], n2 = nrow[2], n3 = nrow[3];
#pragma unroll
            for (int q = 0; q < 4; ++q) {
                aR[q]      = fmaf(wrp[r], n0[q], aR[q]);
                aR[q + 4]  = fmaf(wrp[r], n1[q], aR[q + 4]);
                aR[q + 8]  = fmaf(wrp[r], n2[q], aR[q + 8]);
                aR[q + 12] = fmaf(wrp[r], n3[q], aR[q + 12]);
                aC[q]      = fmaf(wcp[r], n0[q], aC[q]);
                aC[q + 4]  = fmaf(wcp[r], n1[q], aC[q + 4]);
                aC[q + 8]  = fmaf(wcp[r], n2[q], aC[q + 8]);
                aC[q + 12] = fmaf(wcp[r], n3[q], aC[q + 12]);
            }
        }
    }
    float bb = b1[o];
#pragma unroll
    for (int j = 0; j < 16; ++j) {
        int idx = ((b * 256 + j0 + j) << 8) + o;
        Rt[idx] = aR[j] + bb;
        Ctb[idx] = (__bf16)aC[j];
    }
}

// ---------------- main fused kernel ----------------
// 256 thr (4 waves x 64 och), grid 512, 8 n-rows per block.
// NO persistent weights in registers (R1/R2 spilled: compiler caps arch VGPR
// at 128 under launch_bounds(256,2), A2 alone is 128). Instead W2 A-fragments
// are streamed from L2 per tile through a rolling double-buffered quarter
// window (2 x 32 regs). acc[2][2] (64) lives in AGPRs. Peak arch ~120 < 128.
__device__ inline void zero_acc(f32x16 acc[2][2]) {
#pragma unroll
    for (int i = 0; i < 2; ++i)
#pragma unroll
        for (int j = 0; j < 2; ++j)
#pragma unroll
            for (int k = 0; k < 16; ++k) acc[i][j][k] = 0.f;
}

__global__ __launch_bounds__(256, 2) void fused_main(
    const float* __restrict__ edge, const __bf16* __restrict__ w1e,
    const __bf16* __restrict__ w2, const float* __restrict__ Rt,
    const __bf16* __restrict__ Ctb, const float* __restrict__ b2,
    const float* __restrict__ W3, const float* __restrict__ b3,
    float* __restrict__ out) {
    __shared__ unsigned int lds_e[64 * 36];   // edge tile [m][e-pair], stride 36 dw
    __shared__ unsigned int lds_h1[64 * 140]; // h1 tile [pix][ch/2], stride 140 dw
    __shared__ float lds_p[64 * 9];

    const int tid = threadIdx.x;
    const int wid = tid >> 6;
    const int lane = tid & 63;
    const int p31 = lane & 31;
    const int hi = lane >> 5;
    const int obase = wid * 64;

    const int blk = blockIdx.x;
    const int b   = blk >> 7;
    const int m0  = ((blk >> 5) & 3) << 6;
    const int n0  = (blk & 31) << 3;

    const float4* eg = (const float4*)edge;
    const int a_ = tid & 15;
    const int epb = tid >> 4;
    float4 pf[4];

#define PREFETCH(nn)                                                        \
    {                                                                       \
        _Pragma("unroll")                                                   \
        for (int r = 0; r < 2; ++r) {                                       \
            int ep = r * 16 + epb;                                          \
            int f4 = (b * 64 + ep * 2) * 16384 + (nn) * 64 + (m0 >> 2) + a_;\
            pf[r * 2]     = eg[f4];                                         \
            pf[r * 2 + 1] = eg[f4 + 16384];                                 \
        }                                                                   \
    }

    // load one quarter (4 ks x 2 mb fragments) of W2 into buffer bf
#define LOAD_Q(bf, q)                                                       \
    {                                                                       \
        _Pragma("unroll")                                                   \
        for (int ksl = 0; ksl < 4; ++ksl)                                   \
            _Pragma("unroll")                                               \
            for (int mb = 0; mb < 2; ++mb)                                  \
                A2q[bf][ksl][mb] = *(const bf16x8*)(w2 +                    \
                    (obase + mb * 32 + p31) * 256 + ((q) * 4 + ksl) * 16 + hi * 8); \
    }

    PREFETCH(n0);

    f32x16 acc[2][2];
    bf16x8 A2q[2][4][2];
    for (int it = 0; it < 8; ++it) {
        const int n = n0 + it;

        // ---- stage pf -> lds_e (transpose to [m][e], bf16) ----
#pragma unroll
        for (int r = 0; r < 2; ++r) {
            int ep = r * 16 + epb;
            const float* p0 = (const float*)&pf[r * 2];
            const float* p1 = (const float*)&pf[r * 2 + 1];
#pragma unroll
            for (int i = 0; i < 4; ++i) {
                union { __bf16 h[2]; unsigned int u; } t;
                t.h[0] = (__bf16)p0[i];
                t.h[1] = (__bf16)p1[i];
                lds_e[(a_ * 4 + i) * 36 + ep] = t.u;
            }
        }
        // ---- A1 (W1e) fragments: transient, from L2 ----
        bf16x8 A1[2][4];
#pragma unroll
        for (int mb = 0; mb < 2; ++mb)
#pragma unroll
            for (int ks = 0; ks < 4; ++ks)
                A1[mb][ks] = *(const bf16x8*)(w1e + (obase + mb * 32 + p31) * 64 + ks * 16 + hi * 8);
        __syncthreads();

        // ---- layer 1: W1e(64K) @ edge ----
        zero_acc(acc);
#pragma unroll
        for (int ks = 0; ks < 4; ++ks) {
            bf16x8 B1[2];
#pragma unroll
            for (int nb = 0; nb < 2; ++nb)
                B1[nb] = *(const bf16x8*)&lds_e[(nb * 32 + p31) * 36 + ks * 8 + hi * 4];
#pragma unroll
            for (int mb = 0; mb < 2; ++mb) {
                acc[mb][0] = __builtin_amdgcn_mfma_f32_32x32x16_bf16(A1[mb][ks], B1[0], acc[mb][0], 0, 0, 0);
                acc[mb][1] = __builtin_amdgcn_mfma_f32_32x32x16_bf16(A1[mb][ks], B1[1], acc[mb][1], 0, 0, 0);
            }
        }

        // ---- epilogue 1: + Rt[n] (f32) + Ct[m] (bf16), relu -> lds_h1 ----
        const int nRow = (b * 256 + n) << 8;
#pragma unroll
        for (int mb = 0; mb < 2; ++mb) {
#pragma unroll
            for (int rg = 0; rg < 4; ++rg) {
                int och = obase + mb * 32 + 8 * rg + 4 * hi;
                f32x4t Rv = *(const f32x4t*)(Rt + nRow + och);
#pragma unroll
                for (int nb = 0; nb < 2; ++nb) {
                    int pix = nb * 32 + p31;
                    bf16x4v Cv = *(const bf16x4v*)(Ctb + ((b * 256 + m0 + pix) << 8) + och);
                    union { __bf16 h[4]; u32x2 u; } t;
#pragma unroll
                    for (int rr = 0; rr < 4; ++rr) {
                        float v = acc[mb][nb][rg * 4 + rr] + Rv[rr] + (float)Cv[rr];
                        t.h[rr] = (__bf16)fmaxf(v, 0.f);
                    }
                    *(u32x2*)&lds_h1[pix * 140 + (och >> 1)] = t.u;
                }
            }
        }
        // ---- prefetches that overlap the barrier + layer-2 start ----
        LOAD_Q(0, 0);                 // first W2 quarter
        if (it < 7) PREFETCH(n + 1);  // next edge tile
        __syncthreads();

        // ---- layer 2: W2(256K) @ h1, rolling quarter window ----
        zero_acc(acc);
#pragma unroll
        for (int q = 0; q < 4; ++q) {
            if (q < 3) LOAD_Q((q + 1) & 1, q + 1);
#pragma unroll
            for (int ksl = 0; ksl < 4; ++ksl) {
                const int ksg = q * 4 + ksl;
                bf16x8 B2[2];
#pragma unroll
                for (int nb = 0; nb < 2; ++nb)
                    B2[nb] = *(const bf16x8*)&lds_h1[(nb * 32 + p31) * 140 + ksg * 8 + hi * 4];
#pragma unroll
                for (int mb = 0; mb < 2; ++mb) {
                    acc[mb][0] = __builtin_amdgcn_mfma_f32_32x32x16_bf16(A2q[q & 1][ksl][mb], B2[0], acc[mb][0], 0, 0, 0);
                    acc[mb][1] = __builtin_amdgcn_mfma_f32_32x32x16_bf16(A2q[q & 1][ksl][mb], B2[1], acc[mb][1], 0, 0, 0);
                }
            }
        }

        // ---- epilogue 2: +b2, relu, dot W3 (fp32) ----
        float part0 = 0.f, part1 = 0.f;
#pragma unroll
        for (int mb = 0; mb < 2; ++mb) {
#pragma unroll
            for (int rg = 0; rg < 4; ++rg) {
                int och = obase + mb * 32 + 8 * rg + 4 * hi;
                f32x4t b2v = *(const f32x4t*)(b2 + och);
                f32x4t w3v = *(const f32x4t*)(W3 + och);
#pragma unroll
                for (int rr = 0; rr < 4; ++rr) {
                    float h0 = fmaxf(acc[mb][0][rg * 4 + rr] + b2v[rr], 0.f);
                    float h1v = fmaxf(acc[mb][1][rg * 4 + rr] + b2v[rr], 0.f);
                    part0 = fmaf(w3v[rr], h0, part0);
                    part1 = fmaf(w3v[rr], h1v, part1);
                }
            }
        }
        lds_p[(0 * 32 + p31) * 9 + wid * 2 + hi] = part0;
        lds_p[(1 * 32 + p31) * 9 + wid * 2 + hi] = part1;
        __syncthreads();

        if (tid < 64) {
            float s = b3[0];
#pragma unroll
            for (int k = 0; k < 8; ++k) s += lds_p[tid * 9 + k];
            out[((b * 256 + n) << 8) + m0 + tid] = s;
        }
    }
#undef PREFETCH
#undef LOAD_Q
}

extern "C" void kernel_launch(void* const* d_in, const int* in_sizes, int n_in,
                              void* d_out, int out_size, void* d_ws, size_t ws_size,
                              hipStream_t stream) {
    const float* edge = (const float*)d_in[0];
    const float* node = (const float*)d_in[1];
    const float* W1   = (const float*)d_in[2];
    const float* b1   = (const float*)d_in[3];
    const float* W2   = (const float*)d_in[4];
    const float* b2   = (const float*)d_in[5];
    const float* W3   = (const float*)d_in[6];
    const float* b3   = (const float*)d_in[7];
    char* ws = (char*)d_ws;
    __bf16* w1e = (__bf16*)(ws + WS_W1E);
    __bf16* w2b = (__bf16*)(ws + WS_W2);
    float*  Rt  = (float*)(ws + WS_R);
    __bf16* Ctb = (__bf16*)(ws + WS_CT);

    prep_weights<<<320, 256, 0, stream>>>(W1, W2, w1e, w2b);
    prep_rc<<<64, 256, 0, stream>>>(W1, b1, node, Rt, Ctb);
    fused_main<<<512, 256, 0, stream>>>(edge, w1e, w2b, Rt, Ctb, b2, W3, b3, (float*)d_out);
}

// Round 4
// 197.914 us; speedup vs baseline: 1.6479x; 1.6111x over previous
//
#include <hip/hip_runtime.h>
#include <stdint.h>

typedef __bf16 bf16x8 __attribute__((ext_vector_type(8)));
typedef __bf16 bf16x4v __attribute__((ext_vector_type(4)));
typedef float  f32x16 __attribute__((ext_vector_type(16)));
typedef float  f32x4t __attribute__((ext_vector_type(4)));
typedef unsigned int u32x2 __attribute__((ext_vector_type(2)));

// ---- ws layout (bytes) ----
#define WS_W1E 0            // 256*64 bf16  = 32 KB
#define WS_W2  32768        // 256*256 bf16 = 128 KB
#define WS_R   163840       // 4*256*256 f32 = 1 MiB   Rt[b][n][o] (incl. b1)
#define WS_CT  1212416      // 4*256*256 bf16 = 512 KB Ct[b][m][o]

// ---------------- pre-kernel 1: weights -> bf16 ----------------
__global__ void prep_weights(const float* __restrict__ W1, const float* __restrict__ W2,
                             __bf16* __restrict__ w1e, __bf16* __restrict__ w2b) {
    int i = blockIdx.x * 256 + threadIdx.x;
    if (i < 256 * 64) {
        int o = i >> 6, e = i & 63;
        w1e[i] = (__bf16)W1[o * 320 + e];
    }
    int j = i - 256 * 64;
    if (j >= 0 && j < 256 * 256) w2b[j] = (__bf16)W2[j];
}

// ---------------- pre-kernel 2: R/C rank-1 terms ----------------
__global__ __launch_bounds__(256) void prep_rc(
    const float* __restrict__ W1, const float* __restrict__ b1,
    const float* __restrict__ node, float* __restrict__ Rt,
    __bf16* __restrict__ Ctb) {
    __shared__ float nds[128 * 16];
    const int b = blockIdx.x >> 4, j0 = (blockIdx.x & 15) * 16;
    const int o = threadIdx.x;
    {
        int c = threadIdx.x >> 1, jh = (threadIdx.x & 1) * 8;
        const float* src = node + b * 32768 + c * 256 + j0 + jh;
        *(float4*)&nds[c * 16 + jh] = *(const float4*)src;
        *(float4*)&nds[c * 16 + jh + 4] = *(const float4*)(src + 4);
    }
    __syncthreads();
    float aR[16], aC[16];
#pragma unroll
    for (int j = 0; j < 16; ++j) { aR[j] = 0.f; aC[j] = 0.f; }
    const float* wr = W1 + o * 320 + 64;
    const float* wc = W1 + o * 320 + 192;
    for (int c4 = 0; c4 < 32; ++c4) {
        float4 wrv = *(const float4*)(wr + c4 * 4);
        float4 wcv = *(const float4*)(wc + c4 * 4);
        const float* wrp = (const float*)&wrv;
        const float* wcp = (const float*)&wcv;
#pragma unroll
        for (int r = 0; r < 4; ++r) {
            const f32x4t* nrow = (const f32x4t*)&nds[(c4 * 4 + r) * 16];
            f32x4t n0 = nrow[0], n1 = nrow[1], n2 = nrow[2], n3 = nrow[3];
#pragma unroll
            for (int q = 0; q < 4; ++q) {
                aR[q]      = fmaf(wrp[r], n0[q], aR[q]);
                aR[q + 4]  = fmaf(wrp[r], n1[q], aR[q + 4]);
                aR[q + 8]  = fmaf(wrp[r], n2[q], aR[q + 8]);
                aR[q + 12] = fmaf(wrp[r], n3[q], aR[q + 12]);
                aC[q]      = fmaf(wcp[r], n0[q], aC[q]);
                aC[q + 4]  = fmaf(wcp[r], n1[q], aC[q + 4]);
                aC[q + 8]  = fmaf(wcp[r], n2[q], aC[q + 8]);
                aC[q + 12] = fmaf(wcp[r], n3[q], aC[q + 12]);
            }
        }
    }
    float bb = b1[o];
#pragma unroll
    for (int j = 0; j < 16; ++j) {
        int idx = ((b * 256 + j0 + j) << 8) + o;
        Rt[idx] = aR[j] + bb;
        Ctb[idx] = (__bf16)aC[j];
    }
}

// ---------------- main fused kernel ----------------
// 256 thr (4 waves x 64 och), grid 512, 8 n-rows per block.
// W2/W1e A-fragments are STREAMED from L2 each tile. The per-iteration
// asm-volatile address barrier is load-bearing: without it LLVM LICM hoists
// the (loop-invariant) weight loads into 160 persistent regs -> scratch
// spill (R2/R3: 75 MB WRITE_SIZE, MfmaUtil 7.5%). acc reused across layers.
// Peak unified demand ~210 < 256 (2 waves/SIMD budget).
__device__ inline void zero_acc(f32x16 acc[2][2]) {
#pragma unroll
    for (int i = 0; i < 2; ++i)
#pragma unroll
        for (int j = 0; j < 2; ++j)
#pragma unroll
            for (int k = 0; k < 16; ++k) acc[i][j][k] = 0.f;
}

__global__ __launch_bounds__(256, 2) void fused_main(
    const float* __restrict__ edge, const __bf16* __restrict__ w1e,
    const __bf16* __restrict__ w2, const float* __restrict__ Rt,
    const __bf16* __restrict__ Ctb, const float* __restrict__ b2,
    const float* __restrict__ W3, const float* __restrict__ b3,
    float* __restrict__ out) {
    __shared__ unsigned int lds_e[64 * 33];   // edge tile [m][e-pair], stride 33 dw (conflict-free w/ b32 reads)
    __shared__ unsigned int lds_h1[64 * 140]; // h1 tile [pix][ch/2], stride 140 dw
    __shared__ float lds_p[64 * 9];
    __shared__ float lds_c[512];              // [0..255]=b2, [256..511]=W3

    const int tid = threadIdx.x;
    const int wid = tid >> 6;
    const int lane = tid & 63;
    const int p31 = lane & 31;
    const int hi = lane >> 5;
    const int obase = wid * 64;

    const int blk = blockIdx.x;
    const int b   = blk >> 7;
    const int m0  = ((blk >> 5) & 3) << 6;
    const int n0  = (blk & 31) << 3;

    lds_c[tid] = b2[tid];
    lds_c[256 + tid] = W3[tid];

    const float4* eg = (const float4*)edge;
    const int a_ = tid & 15;
    const int epb = tid >> 4;
    float4 pf[4];

#define PREFETCH(nn)                                                        \
    {                                                                       \
        _Pragma("unroll")                                                   \
        for (int r = 0; r < 2; ++r) {                                       \
            int ep = r * 16 + epb;                                          \
            int f4 = (b * 64 + ep * 2) * 16384 + (nn) * 64 + (m0 >> 2) + a_;\
            pf[r * 2]     = eg[f4];                                         \
            pf[r * 2 + 1] = eg[f4 + 16384];                                 \
        }                                                                   \
    }

#define LOAD_Q(bf, q)                                                       \
    {                                                                       \
        _Pragma("unroll")                                                   \
        for (int ksl = 0; ksl < 4; ++ksl)                                   \
            _Pragma("unroll")                                               \
            for (int mb = 0; mb < 2; ++mb)                                  \
                A2q[bf][ksl][mb] = *(const bf16x8*)(w2_s +                  \
                    (obase + mb * 32 + p31) * 256 + ((q) * 4 + ksl) * 16 + hi * 8); \
    }

    PREFETCH(n0);

    // ---- explicitly hoisted it-invariant Ct fragments (32 regs) ----
    bf16x4v CvR[8][2];
#pragma unroll
    for (int mb = 0; mb < 2; ++mb)
#pragma unroll
        for (int rg = 0; rg < 4; ++rg)
#pragma unroll
            for (int nb = 0; nb < 2; ++nb)
                CvR[mb * 4 + rg][nb] = *(const bf16x4v*)(Ctb +
                    ((b * 256 + m0 + nb * 32 + p31) << 8) + obase + mb * 32 + 8 * rg + 4 * hi);

    f32x16 acc[2][2];
    bf16x8 A2q[2][4][2];
    for (int it = 0; it < 8; ++it) {
        const int n = n0 + it;

        // opaque per-iteration address barriers: defeat LICM/CSE of weight loads
        uint64_t w1a = (uint64_t)w1e;
        asm volatile("" : "+s"(w1a));
        const __bf16* w1e_s = (const __bf16*)w1a;
        uint64_t w2a = (uint64_t)w2;
        asm volatile("" : "+s"(w2a));
        const __bf16* w2_s = (const __bf16*)w2a;

        // ---- stage pf -> lds_e (transpose to [m][e], bf16) ----
#pragma unroll
        for (int r = 0; r < 2; ++r) {
            int ep = r * 16 + epb;
            const float* p0 = (const float*)&pf[r * 2];
            const float* p1 = (const float*)&pf[r * 2 + 1];
#pragma unroll
            for (int i = 0; i < 4; ++i) {
                union { __bf16 h[2]; unsigned int u; } t;
                t.h[0] = (__bf16)p0[i];
                t.h[1] = (__bf16)p1[i];
                lds_e[(a_ * 4 + i) * 33 + ep] = t.u;
            }
        }
        // ---- A1 (W1e) fragments: streamed from L2 this tile ----
        bf16x8 A1[2][4];
#pragma unroll
        for (int mb = 0; mb < 2; ++mb)
#pragma unroll
            for (int ks = 0; ks < 4; ++ks)
                A1[mb][ks] = *(const bf16x8*)(w1e_s + (obase + mb * 32 + p31) * 64 + ks * 16 + hi * 8);
        __syncthreads();

        // ---- layer 1: W1e(64K) @ edge ----
        zero_acc(acc);
#pragma unroll
        for (int ks = 0; ks < 4; ++ks) {
            bf16x8 B1[2];
#pragma unroll
            for (int nb = 0; nb < 2; ++nb) {
                union { unsigned int u[4]; bf16x8 v; } bb;
#pragma unroll
                for (int j = 0; j < 4; ++j)
                    bb.u[j] = lds_e[(nb * 32 + p31) * 33 + ks * 8 + hi * 4 + j];
                B1[nb] = bb.v;
            }
#pragma unroll
            for (int mb = 0; mb < 2; ++mb) {
                acc[mb][0] = __builtin_amdgcn_mfma_f32_32x32x16_bf16(A1[mb][ks], B1[0], acc[mb][0], 0, 0, 0);
                acc[mb][1] = __builtin_amdgcn_mfma_f32_32x32x16_bf16(A1[mb][ks], B1[1], acc[mb][1], 0, 0, 0);
            }
        }

        // ---- epilogue 1: + Rt[n] (f32, global L2) + Ct (regs), relu -> lds_h1 ----
        const int nRow = (b * 256 + n) << 8;
#pragma unroll
        for (int mb = 0; mb < 2; ++mb) {
#pragma unroll
            for (int rg = 0; rg < 4; ++rg) {
                int och = obase + mb * 32 + 8 * rg + 4 * hi;
                f32x4t Rv = *(const f32x4t*)(Rt + nRow + och);
#pragma unroll
                for (int nb = 0; nb < 2; ++nb) {
                    int pix = nb * 32 + p31;
                    bf16x4v Cv = CvR[mb * 4 + rg][nb];
                    union { __bf16 h[4]; u32x2 u; } t;
#pragma unroll
                    for (int rr = 0; rr < 4; ++rr) {
                        float v = acc[mb][nb][rg * 4 + rr] + Rv[rr] + (float)Cv[rr];
                        t.h[rr] = (__bf16)fmaxf(v, 0.f);
                    }
                    *(u32x2*)&lds_h1[pix * 140 + (och >> 1)] = t.u;
                }
            }
        }
        // ---- prefetches overlapping the barrier + layer-2 start ----
        LOAD_Q(0, 0);
        if (it < 7) PREFETCH(n + 1);
        __syncthreads();

        // ---- layer 2: W2(256K) @ h1, rolling streamed quarter window ----
        zero_acc(acc);
#pragma unroll
        for (int q = 0; q < 4; ++q) {
            if (q < 3) LOAD_Q((q + 1) & 1, q + 1);
#pragma unroll
            for (int ksl = 0; ksl < 4; ++ksl) {
                const int ksg = q * 4 + ksl;
                bf16x8 B2[2];
#pragma unroll
                for (int nb = 0; nb < 2; ++nb)
                    B2[nb] = *(const bf16x8*)&lds_h1[(nb * 32 + p31) * 140 + ksg * 8 + hi * 4];
#pragma unroll
                for (int mb = 0; mb < 2; ++mb) {
                    acc[mb][0] = __builtin_amdgcn_mfma_f32_32x32x16_bf16(A2q[q & 1][ksl][mb], B2[0], acc[mb][0], 0, 0, 0);
                    acc[mb][1] = __builtin_amdgcn_mfma_f32_32x32x16_bf16(A2q[q & 1][ksl][mb], B2[1], acc[mb][1], 0, 0, 0);
                }
            }
        }

        // ---- epilogue 2: +b2, relu, dot W3 (fp32, from LDS) ----
        float part0 = 0.f, part1 = 0.f;
#pragma unroll
        for (int mb = 0; mb < 2; ++mb) {
#pragma unroll
            for (int rg = 0; rg < 4; ++rg) {
                int och = obase + mb * 32 + 8 * rg + 4 * hi;
                f32x4t b2v = *(const f32x4t*)&lds_c[och];
                f32x4t w3v = *(const f32x4t*)&lds_c[256 + och];
#pragma unroll
                for (int rr = 0; rr < 4; ++rr) {
                    float h0 = fmaxf(acc[mb][0][rg * 4 + rr] + b2v[rr], 0.f);
                    float h1v = fmaxf(acc[mb][1][rg * 4 + rr] + b2v[rr], 0.f);
                    part0 = fmaf(w3v[rr], h0, part0);
                    part1 = fmaf(w3v[rr], h1v, part1);
                }
            }
        }
        lds_p[(0 * 32 + p31) * 9 + wid * 2 + hi] = part0;
        lds_p[(1 * 32 + p31) * 9 + wid * 2 + hi] = part1;
        __syncthreads();

        if (tid < 64) {
            float s = b3[0];
#pragma unroll
            for (int k = 0; k < 8; ++k) s += lds_p[tid * 9 + k];
            out[((b * 256 + n) << 8) + m0 + tid] = s;
        }
    }
#undef PREFETCH
#undef LOAD_Q
}

extern "C" void kernel_launch(void* const* d_in, const int* in_sizes, int n_in,
                              void* d_out, int out_size, void* d_ws, size_t ws_size,
                              hipStream_t stream) {
    const float* edge = (const float*)d_in[0];
    const float* node = (const float*)d_in[1];
    const float* W1   = (const float*)d_in[2];
    const float* b1   = (const float*)d_in[3];
    const float* W2   = (const float*)d_in[4];
    const float* b2   = (const float*)d_in[5];
    const float* W3   = (const float*)d_in[6];
    const float* b3   = (const float*)d_in[7];
    char* ws = (char*)d_ws;
    __bf16* w1e = (__bf16*)(ws + WS_W1E);
    __bf16* w2b = (__bf16*)(ws + WS_W2);
    float*  Rt  = (float*)(ws + WS_R);
    __bf16* Ctb = (__bf16*)(ws + WS_CT);

    prep_weights<<<320, 256, 0, stream>>>(W1, W2, w1e, w2b);
    prep_rc<<<64, 256, 0, stream>>>(W1, b1, node, Rt, Ctb);
    fused_main<<<512, 256, 0, stream>>>(edge, w1e, w2b, Rt, Ctb, b2, W3, b3, (float*)d_out);
}

// Round 5
// 160.240 us; speedup vs baseline: 2.0353x; 1.2351x over previous
//
#include <hip/hip_runtime.h>
#include <stdint.h>

typedef __bf16 bf16x8 __attribute__((ext_vector_type(8)));
typedef __bf16 bf16x4v __attribute__((ext_vector_type(4)));
typedef float  f32x16 __attribute__((ext_vector_type(16)));
typedef float  f32x4t __attribute__((ext_vector_type(4)));
typedef unsigned int u32x2 __attribute__((ext_vector_type(2)));

// ---- ws layout (bytes) ----
#define WS_W1S 0            // 32 chunks  * 1 KB = 32 KB   W1e fragment-swizzled
#define WS_W2S 32768        // 128 chunks * 1 KB = 128 KB  W2 fragment-swizzled
#define WS_R   163840       // 4*256*256 f32 = 1 MiB   Rt[b][n][o] (incl. b1)
#define WS_CT  1212416      // 4*256*256 bf16 = 512 KB Ct[b][m][o]

// ---------------- pre-kernel 1: weights -> bf16, MFMA-fragment-swizzled ----
// Chunk = (wid, ks, mb); within chunk: lane*8 bf16 (16 B). Fragment mapping
// (must match fused_main's MFMA operand layout): o = wid*64 + mb*32 + (lane&31),
// k = ks*16 + (lane>>5)*8 + j. Makes hot-loop A-loads lane-consecutive
// (R4 post-mortem: row-gather A-loads = ~64 lines/instr = the 102 us stall).
__global__ void prep_weights(const float* __restrict__ W1, const float* __restrict__ W2,
                             __bf16* __restrict__ w1s, __bf16* __restrict__ w2s) {
    int t = blockIdx.x * 256 + threadIdx.x;   // 40*256 = 10240 = 160 chunks * 64 lanes
    int chunk = t >> 6, lane = t & 63;
    if (chunk < 128) {                        // W2: 4 wid x 16 ks x 2 mb
        int wid = chunk >> 5, ks = (chunk >> 1) & 15, mb = chunk & 1;
        int o = wid * 64 + mb * 32 + (lane & 31);
        int k = ks * 16 + (lane >> 5) * 8;
        const float* src = W2 + o * 256 + k;
        __bf16* dst = w2s + chunk * 512 + lane * 8;
#pragma unroll
        for (int j = 0; j < 8; ++j) dst[j] = (__bf16)src[j];
    } else if (chunk < 160) {                 // W1e: 4 wid x 4 ks x 2 mb
        int c1 = chunk - 128;
        int wid = c1 >> 3, ks = (c1 >> 1) & 3, mb = c1 & 1;
        int o = wid * 64 + mb * 32 + (lane & 31);
        int k = ks * 16 + (lane >> 5) * 8;
        const float* src = W1 + o * 320 + k;
        __bf16* dst = w1s + c1 * 512 + lane * 8;
#pragma unroll
        for (int j = 0; j < 8; ++j) dst[j] = (__bf16)src[j];
    }
}

// ---------------- pre-kernel 2: R/C rank-1 terms ----------------
__global__ __launch_bounds__(256) void prep_rc(
    const float* __restrict__ W1, const float* __restrict__ b1,
    const float* __restrict__ node, float* __restrict__ Rt,
    __bf16* __restrict__ Ctb) {
    __shared__ float nds[128 * 16];
    const int b = blockIdx.x >> 4, j0 = (blockIdx.x & 15) * 16;
    const int o = threadIdx.x;
    {
        int c = threadIdx.x >> 1, jh = (threadIdx.x & 1) * 8;
        const float* src = node + b * 32768 + c * 256 + j0 + jh;
        *(float4*)&nds[c * 16 + jh] = *(const float4*)src;
        *(float4*)&nds[c * 16 + jh + 4] = *(const float4*)(src + 4);
    }
    __syncthreads();
    float aR[16], aC[16];
#pragma unroll
    for (int j = 0; j < 16; ++j) { aR[j] = 0.f; aC[j] = 0.f; }
    const float* wr = W1 + o * 320 + 64;
    const float* wc = W1 + o * 320 + 192;
    for (int c4 = 0; c4 < 32; ++c4) {
        float4 wrv = *(const float4*)(wr + c4 * 4);
        float4 wcv = *(const float4*)(wc + c4 * 4);
        const float* wrp = (const float*)&wrv;
        const float* wcp = (const float*)&wcv;
#pragma unroll
        for (int r = 0; r < 4; ++r) {
            const f32x4t* nrow = (const f32x4t*)&nds[(c4 * 4 + r) * 16];
            f32x4t n0 = nrow[0], n1 = nrow[1], n2 = nrow[2], n3 = nrow[3];
#pragma unroll
            for (int q = 0; q < 4; ++q) {
                aR[q]      = fmaf(wrp[r], n0[q], aR[q]);
                aR[q + 4]  = fmaf(wrp[r], n1[q], aR[q + 4]);
                aR[q + 8]  = fmaf(wrp[r], n2[q], aR[q + 8]);
                aR[q + 12] = fmaf(wrp[r], n3[q], aR[q + 12]);
                aC[q]      = fmaf(wcp[r], n0[q], aC[q]);
                aC[q + 4]  = fmaf(wcp[r], n1[q], aC[q + 4]);
                aC[q + 8]  = fmaf(wcp[r], n2[q], aC[q + 8]);
                aC[q + 12] = fmaf(wcp[r], n3[q], aC[q + 12]);
            }
        }
    }
    float bb = b1[o];
#pragma unroll
    for (int j = 0; j < 16; ++j) {
        int idx = ((b * 256 + j0 + j) << 8) + o;
        Rt[idx] = aR[j] + bb;
        Ctb[idx] = (__bf16)aC[j];
    }
}

// ---------------- main fused kernel ----------------
// 256 thr (4 waves x 64 och), grid 512, 8 n-rows per block.
// Weight A-fragments streamed from L2 each tile via SWIZZLED layout ->
// fully coalesced (1 KB contiguous per wave-load). asm barrier per iteration
// is load-bearing: defeats LICM re-hoist into persistent regs -> spill
// (R2/R3 lesson: 75 MB scratch WRITE, MfmaUtil 7.5%).
__device__ inline void zero_acc(f32x16 acc[2][2]) {
#pragma unroll
    for (int i = 0; i < 2; ++i)
#pragma unroll
        for (int j = 0; j < 2; ++j)
#pragma unroll
            for (int k = 0; k < 16; ++k) acc[i][j][k] = 0.f;
}

__global__ __launch_bounds__(256, 2) void fused_main(
    const float* __restrict__ edge, const __bf16* __restrict__ w1s,
    const __bf16* __restrict__ w2s, const float* __restrict__ Rt,
    const __bf16* __restrict__ Ctb, const float* __restrict__ b2,
    const float* __restrict__ W3, const float* __restrict__ b3,
    float* __restrict__ out) {
    __shared__ unsigned int lds_e[64 * 33];   // edge tile [m][e-pair], stride 33 dw
    __shared__ unsigned int lds_h1[64 * 140]; // h1 tile [pix][ch/2], stride 140 dw
    __shared__ float lds_p[64 * 9];
    __shared__ float lds_c[512];              // [0..255]=b2, [256..511]=W3

    const int tid = threadIdx.x;
    const int wid = tid >> 6;
    const int lane = tid & 63;
    const int p31 = lane & 31;
    const int hi = lane >> 5;
    const int obase = wid * 64;

    const int blk = blockIdx.x;
    const int b   = blk >> 7;
    const int m0  = ((blk >> 5) & 3) << 6;
    const int n0  = (blk & 31) << 3;

    lds_c[tid] = b2[tid];
    lds_c[256 + tid] = W3[tid];

    const float4* eg = (const float4*)edge;
    const int a_ = tid & 15;
    const int epb = tid >> 4;
    float4 pf[4];

#define PREFETCH(nn)                                                        \
    {                                                                       \
        _Pragma("unroll")                                                   \
        for (int r = 0; r < 2; ++r) {                                       \
            int ep = r * 16 + epb;                                          \
            int f4 = (b * 64 + ep * 2) * 16384 + (nn) * 64 + (m0 >> 2) + a_;\
            pf[r * 2]     = eg[f4];                                         \
            pf[r * 2 + 1] = eg[f4 + 16384];                                 \
        }                                                                   \
    }

    // coalesced: chunk = (wid*16 + ksg)*2 + mb, lane-consecutive 16 B
#define LOAD_Q(bf, q)                                                       \
    {                                                                       \
        _Pragma("unroll")                                                   \
        for (int ksl = 0; ksl < 4; ++ksl)                                   \
            _Pragma("unroll")                                               \
            for (int mb = 0; mb < 2; ++mb)                                  \
                A2q[bf][ksl][mb] = *(const bf16x8*)(w2_s +                  \
                    ((((wid << 4) + (q) * 4 + ksl) << 1) + mb) * 512 + (lane << 3)); \
    }

    PREFETCH(n0);

    // ---- hoisted it-invariant Ct fragments (32 regs, gather once/block) ----
    bf16x4v CvR[8][2];
#pragma unroll
    for (int mb = 0; mb < 2; ++mb)
#pragma unroll
        for (int rg = 0; rg < 4; ++rg)
#pragma unroll
            for (int nb = 0; nb < 2; ++nb)
                CvR[mb * 4 + rg][nb] = *(const bf16x4v*)(Ctb +
                    ((b * 256 + m0 + nb * 32 + p31) << 8) + obase + mb * 32 + 8 * rg + 4 * hi);

    f32x16 acc[2][2];
    bf16x8 A2q[2][4][2];
    for (int it = 0; it < 8; ++it) {
        const int n = n0 + it;

        // opaque per-iteration address barriers: defeat LICM/CSE of weight loads
        uint64_t w1a = (uint64_t)w1s;
        asm volatile("" : "+s"(w1a));
        const __bf16* w1_s = (const __bf16*)w1a;
        uint64_t w2a = (uint64_t)w2s;
        asm volatile("" : "+s"(w2a));
        const __bf16* w2_s = (const __bf16*)w2a;

        // ---- stage pf -> lds_e (transpose to [m][e], bf16) ----
#pragma unroll
        for (int r = 0; r < 2; ++r) {
            int ep = r * 16 + epb;
            const float* p0 = (const float*)&pf[r * 2];
            const float* p1 = (const float*)&pf[r * 2 + 1];
#pragma unroll
            for (int i = 0; i < 4; ++i) {
                union { __bf16 h[2]; unsigned int u; } t;
                t.h[0] = (__bf16)p0[i];
                t.h[1] = (__bf16)p1[i];
                lds_e[(a_ * 4 + i) * 33 + ep] = t.u;
            }
        }
        // ---- A1 (W1e) fragments: coalesced stream from L2 ----
        bf16x8 A1[2][4];
#pragma unroll
        for (int mb = 0; mb < 2; ++mb)
#pragma unroll
            for (int ks = 0; ks < 4; ++ks)
                A1[mb][ks] = *(const bf16x8*)(w1_s +
                    ((((wid << 2) + ks) << 1) + mb) * 512 + (lane << 3));
        __syncthreads();

        // ---- layer 1: W1e(64K) @ edge ----
        zero_acc(acc);
#pragma unroll
        for (int ks = 0; ks < 4; ++ks) {
            bf16x8 B1[2];
#pragma unroll
            for (int nb = 0; nb < 2; ++nb) {
                union { unsigned int u[4]; bf16x8 v; } bb;
#pragma unroll
                for (int j = 0; j < 4; ++j)
                    bb.u[j] = lds_e[(nb * 32 + p31) * 33 + ks * 8 + hi * 4 + j];
                B1[nb] = bb.v;
            }
#pragma unroll
            for (int mb = 0; mb < 2; ++mb) {
                acc[mb][0] = __builtin_amdgcn_mfma_f32_32x32x16_bf16(A1[mb][ks], B1[0], acc[mb][0], 0, 0, 0);
                acc[mb][1] = __builtin_amdgcn_mfma_f32_32x32x16_bf16(A1[mb][ks], B1[1], acc[mb][1], 0, 0, 0);
            }
        }

        // ---- epilogue 1: + Rt[n] (broadcast L2) + Ct (regs), relu -> lds_h1 ----
        const int nRow = (b * 256 + n) << 8;
#pragma unroll
        for (int mb = 0; mb < 2; ++mb) {
#pragma unroll
            for (int rg = 0; rg < 4; ++rg) {
                int och = obase + mb * 32 + 8 * rg + 4 * hi;
                f32x4t Rv = *(const f32x4t*)(Rt + nRow + och);
#pragma unroll
                for (int nb = 0; nb < 2; ++nb) {
                    int pix = nb * 32 + p31;
                    bf16x4v Cv = CvR[mb * 4 + rg][nb];
                    union { __bf16 h[4]; u32x2 u; } t;
#pragma unroll
                    for (int rr = 0; rr < 4; ++rr) {
                        float v = acc[mb][nb][rg * 4 + rr] + Rv[rr] + (float)Cv[rr];
                        t.h[rr] = (__bf16)fmaxf(v, 0.f);
                    }
                    *(u32x2*)&lds_h1[pix * 140 + (och >> 1)] = t.u;
                }
            }
        }
        // ---- prefetches overlapping the barrier + layer-2 start ----
        LOAD_Q(0, 0);
        if (it < 7) PREFETCH(n + 1);
        __syncthreads();

        // ---- layer 2: W2(256K) @ h1, rolling streamed quarter window ----
        zero_acc(acc);
#pragma unroll
        for (int q = 0; q < 4; ++q) {
            if (q < 3) LOAD_Q((q + 1) & 1, q + 1);
#pragma unroll
            for (int ksl = 0; ksl < 4; ++ksl) {
                const int ksg = q * 4 + ksl;
                bf16x8 B2[2];
#pragma unroll
                for (int nb = 0; nb < 2; ++nb)
                    B2[nb] = *(const bf16x8*)&lds_h1[(nb * 32 + p31) * 140 + ksg * 8 + hi * 4];
#pragma unroll
                for (int mb = 0; mb < 2; ++mb) {
                    acc[mb][0] = __builtin_amdgcn_mfma_f32_32x32x16_bf16(A2q[q & 1][ksl][mb], B2[0], acc[mb][0], 0, 0, 0);
                    acc[mb][1] = __builtin_amdgcn_mfma_f32_32x32x16_bf16(A2q[q & 1][ksl][mb], B2[1], acc[mb][1], 0, 0, 0);
                }
            }
        }

        // ---- epilogue 2: +b2, relu, dot W3 (fp32, from LDS) ----
        float part0 = 0.f, part1 = 0.f;
#pragma unroll
        for (int mb = 0; mb < 2; ++mb) {
#pragma unroll
            for (int rg = 0; rg < 4; ++rg) {
                int och = obase + mb * 32 + 8 * rg + 4 * hi;
                f32x4t b2v = *(const f32x4t*)&lds_c[och];
                f32x4t w3v = *(const f32x4t*)&lds_c[256 + och];
#pragma unroll
                for (int rr = 0; rr < 4; ++rr) {
                    float h0 = fmaxf(acc[mb][0][rg * 4 + rr] + b2v[rr], 0.f);
                    float h1v = fmaxf(acc[mb][1][rg * 4 + rr] + b2v[rr], 0.f);
                    part0 = fmaf(w3v[rr], h0, part0);
                    part1 = fmaf(w3v[rr], h1v, part1);
                }
            }
        }
        lds_p[(0 * 32 + p31) * 9 + wid * 2 + hi] = part0;
        lds_p[(1 * 32 + p31) * 9 + wid * 2 + hi] = part1;
        __syncthreads();

        if (tid < 64) {
            float s = b3[0];
#pragma unroll
            for (int k = 0; k < 8; ++k) s += lds_p[tid * 9 + k];
            out[((b * 256 + n) << 8) + m0 + tid] = s;
        }
    }
#undef PREFETCH
#undef LOAD_Q
}

extern "C" void kernel_launch(void* const* d_in, const int* in_sizes, int n_in,
                              void* d_out, int out_size, void* d_ws, size_t ws_size,
                              hipStream_t stream) {
    const float* edge = (const float*)d_in[0];
    const float* node = (const float*)d_in[1];
    const float* W1   = (const float*)d_in[2];
    const float* b1   = (const float*)d_in[3];
    const float* W2   = (const float*)d_in[4];
    const float* b2   = (const float*)d_in[5];
    const float* W3   = (const float*)d_in[6];
    const float* b3   = (const float*)d_in[7];
    char* ws = (char*)d_ws;
    __bf16* w1s = (__bf16*)(ws + WS_W1S);
    __bf16* w2s = (__bf16*)(ws + WS_W2S);
    float*  Rt  = (float*)(ws + WS_R);
    __bf16* Ctb = (__bf16*)(ws + WS_CT);

    prep_weights<<<40, 256, 0, stream>>>(W1, W2, w1s, w2s);
    prep_rc<<<64, 256, 0, stream>>>(W1, b1, node, Rt, Ctb);
    fused_main<<<512, 256, 0, stream>>>(edge, w1s, w2s, Rt, Ctb, b2, W3, b3, (float*)d_out);
}